// Round 1
// baseline (72.895 us; speedup 1.0000x reference)
//
#include <hip/hip_runtime.h>
#include <hip/hip_bf16.h>
#include <math.h>

#define HALF_LOG_2PI 0.9189385332046727f
#define WIN 32.0f
#define TILE_T 4

// ---------------------------------------------------------------------------
// Kernel 0: detect mask dtype. Reads first B*Tin bytes (safe under all
// interpretations) as words. int32 0/1 -> mode 0; f32 0.0/1.0 -> mode 1;
// packed bytes -> mode 2.
// ---------------------------------------------------------------------------
__global__ void detect_mask_mode_k(const unsigned int* __restrict__ mw,
                                   int nwords, int* __restrict__ mode) {
    __shared__ int s_not[2];
    if (threadIdx.x == 0) { s_not[0] = 0; s_not[1] = 0; }
    __syncthreads();
    int notInt = 0, notF32 = 0;
    for (int i = threadIdx.x; i < nwords; i += blockDim.x) {
        unsigned int w = mw[i];
        notInt |= (w != 0u && w != 1u);
        notF32 |= (w != 0u && w != 0x3F800000u);
    }
    if (notInt) atomicOr(&s_not[0], 1);
    if (notF32) atomicOr(&s_not[1], 1);
    __syncthreads();
    if (threadIdx.x == 0)
        *mode = (!s_not[0]) ? 0 : ((!s_not[1]) ? 1 : 2);
}

// ---------------------------------------------------------------------------
// Kernel 1: per-row cumsum (center), amp = mask ? 0 : 1/(sigma*sqrt(2pi)),
// inv_sigma. One block per batch row, blockDim = Tin.
// ---------------------------------------------------------------------------
__global__ void prep_k(const float* __restrict__ duration,
                       const float* __restrict__ sigma,
                       const void* __restrict__ mask,
                       const int* __restrict__ mode_p,
                       float* __restrict__ center,
                       float* __restrict__ amp,
                       float* __restrict__ inv_sigma,
                       int Tin) {
    __shared__ float s[1024];
    int b = blockIdx.x;
    int i = threadIdx.x;
    size_t gi = (size_t)b * Tin + i;
    float d = duration[gi];
    s[i] = d;
    __syncthreads();
    // Hillis-Steele inclusive scan
    for (int off = 1; off < Tin; off <<= 1) {
        float v = (i >= off) ? s[i - off] : 0.0f;
        __syncthreads();
        s[i] += v;
        __syncthreads();
    }
    float c = s[i] - 0.5f * d;
    int mode = *mode_p;
    bool m;
    if (mode == 0)      m = ((const int*)mask)[gi] != 0;
    else if (mode == 1) m = ((const float*)mask)[gi] != 0.0f;
    else                m = ((const unsigned char*)mask)[gi] != 0;
    float sg = sigma[gi];
    center[gi]    = c;
    inv_sigma[gi] = 1.0f / sg;
    amp[gi]       = m ? 0.0f : __expf(-__logf(sg) - HALF_LOG_2PI);
}

// ---------------------------------------------------------------------------
// Kernel 2: denom[b,t] = sum_i alignment + 1e-8; also window lo/cnt per (b,t).
// Grid (Tout/256, B), 256 threads, centers/amp/inv staged in LDS.
// ---------------------------------------------------------------------------
__global__ __launch_bounds__(256) void denom_k(
        const float* __restrict__ center, const float* __restrict__ amp,
        const float* __restrict__ inv_sigma,
        float* __restrict__ denom, int* __restrict__ lo_out,
        int* __restrict__ cnt_out, int Tin, int Tout) {
    __shared__ float sc[1024], sa[1024], si[1024];
    int b = blockIdx.y;
    int t = blockIdx.x * 256 + threadIdx.x;
    for (int i = threadIdx.x; i < Tin; i += 256) {
        size_t g = (size_t)b * Tin + i;
        sc[i] = center[g]; sa[i] = amp[g]; si[i] = inv_sigma[g];
    }
    __syncthreads();
    if (t >= Tout) return;
    float tf = (float)t;
    // lower bound: first i with sc[i] >= tf - WIN
    int lo = 0, hi = Tin;
    while (lo < hi) {
        int mid = (lo + hi) >> 1;
        if (sc[mid] < tf - WIN) lo = mid + 1; else hi = mid;
    }
    float sum = 0.0f;
    int i = lo;
    for (; i < Tin; ++i) {
        float c = sc[i];
        if (c > tf + WIN) break;
        float z = (tf - c) * si[i];
        sum += sa[i] * __expf(-0.5f * z * z);
    }
    size_t g = (size_t)b * Tout + t;
    denom[g]   = sum + 1e-8f;
    lo_out[g]  = lo;
    cnt_out[g] = i - lo;
}

// ---------------------------------------------------------------------------
// Kernel 3: attn_weights rows. One block per (b,i); fully coalesced float4
// writes of the Tout-length row (zeros outside the window).
// ---------------------------------------------------------------------------
__global__ __launch_bounds__(256) void attn_k(
        const float* __restrict__ center, const float* __restrict__ amp,
        const float* __restrict__ inv_sigma, const float* __restrict__ denom,
        float* __restrict__ attn, int Tin, int Tout) {
    int bi = blockIdx.x;
    int b = bi / Tin;
    float c = center[bi], a = amp[bi], inv = inv_sigma[bi];
    const float* den = denom + (size_t)b * Tout;
    float* row = attn + (size_t)bi * Tout;
    for (int t4 = threadIdx.x * 4; t4 < Tout; t4 += 256 * 4) {
        float r[4];
        // quick whole-quad rejection (window is only 64 wide)
        if ((float)(t4 + 3) < c - WIN || (float)t4 > c + WIN) {
            r[0] = r[1] = r[2] = r[3] = 0.0f;
        } else {
            #pragma unroll
            for (int j = 0; j < 4; ++j) {
                float tf = (float)(t4 + j);
                float dlt = tf - c;
                if (fabsf(dlt) < WIN) {
                    float z = dlt * inv;
                    r[j] = a * __expf(-0.5f * z * z) / den[t4 + j];
                } else {
                    r[j] = 0.0f;
                }
            }
        }
        *(float4*)(row + t4) = make_float4(r[0], r[1], r[2], r[3]);
    }
}

// ---------------------------------------------------------------------------
// Kernel 4: upsampled[b,t,d] = sum_w attn[b,lo+w,t] * memory[b,lo+w,d].
// Block = (b, 4-frame tile); 256 threads over D. Weights (4 x 128) staged in
// LDS (broadcast reads during MAC); memory rows read coalesced from global
// (L2-resident thanks to XCD-chunked swizzle: each XCD owns contiguous b's).
// ---------------------------------------------------------------------------
__global__ __launch_bounds__(256) void upsample_k(
        const float* __restrict__ mem, const float* __restrict__ center,
        const float* __restrict__ amp, const float* __restrict__ inv_sigma,
        const float* __restrict__ denom, const int* __restrict__ lo_ws,
        const int* __restrict__ cnt_ws, float* __restrict__ out,
        int Tin, int Tout, int D) {
    __shared__ float w_s[TILE_T][128];
    __shared__ int s_lo, s_cnt;
    int nwg = gridDim.x;
    int wid = blockIdx.x;
    int work = wid;
    if ((nwg & 7) == 0) {                    // XCD-chunked swizzle (8 XCDs)
        int chunk = nwg >> 3;
        work = (wid & 7) * chunk + (wid >> 3);
    }
    int tpb = Tout / TILE_T;
    int b  = work / tpb;
    int t0 = (work % tpb) * TILE_T;
    int tid = threadIdx.x;
    if (tid == 0) {
        int lo0 = lo_ws[(size_t)b * Tout + t0];
        size_t g3 = (size_t)b * Tout + t0 + TILE_T - 1;
        int hi = lo_ws[g3] + cnt_ws[g3];
        s_lo = lo0;
        s_cnt = hi - lo0;
    }
    __syncthreads();
    int lo0 = s_lo;
    int wcnt = s_cnt;
    if (wcnt > 128) wcnt = 128;   // mathematically <= 68 (spacing >= 1)
    // weights: TILE_T*128 slots, 2 per thread
    #pragma unroll
    for (int rep = 0; rep < 2; ++rep) {
        int id = tid + rep * 256;
        int f = id >> 7;          // 0..3
        int w = id & 127;
        float wgt = 0.0f;
        int i = lo0 + w;
        if (w < wcnt && i < Tin) {
            float tf = (float)(t0 + f);
            size_t gi = (size_t)b * Tin + i;
            float c = center[gi];
            float dlt = tf - c;
            if (fabsf(dlt) < WIN) {
                float z = dlt * inv_sigma[gi];
                wgt = amp[gi] * __expf(-0.5f * z * z)
                      / denom[(size_t)b * Tout + t0 + f];
            }
        }
        w_s[f][w] = wgt;
    }
    __syncthreads();
    for (int d = tid; d < D; d += 256) {
        float acc0 = 0.f, acc1 = 0.f, acc2 = 0.f, acc3 = 0.f;
        const float* mrow = mem + ((size_t)b * Tin + lo0) * D + d;
        for (int w = 0; w < wcnt; ++w) {
            float m = mrow[(size_t)w * D];
            acc0 += w_s[0][w] * m;
            acc1 += w_s[1][w] * m;
            acc2 += w_s[2][w] * m;
            acc3 += w_s[3][w] * m;
        }
        float* orow = out + ((size_t)b * Tout + t0) * D + d;
        orow[0]          = acc0;
        orow[(size_t)D]  = acc1;
        orow[2*(size_t)D] = acc2;
        orow[3*(size_t)D] = acc3;
    }
}

extern "C" void kernel_launch(void* const* d_in, const int* in_sizes, int n_in,
                              void* d_out, int out_size, void* d_ws, size_t ws_size,
                              hipStream_t stream) {
    const float* memory   = (const float*)d_in[0];
    const float* duration = (const float*)d_in[1];
    const float* sigma    = (const float*)d_in[2];
    // d_in[3] = output_lengths (all equal Tout; unused — reference ignores it
    // beyond Tout = max, which is fixed by the output allocation)
    const void* mask = d_in[4];

    int B   = in_sizes[3];
    int Tin = in_sizes[1] / B;
    int D   = in_sizes[0] / (B * Tin);
    int Tout = out_size / (B * (D + Tin));

    float* out_up   = (float*)d_out;
    float* out_attn = out_up + (size_t)B * Tout * D;

    // workspace layout
    char* w = (char*)d_ws;
    int*   mode   = (int*)w;
    float* center = (float*)(w + 256);
    float* amp    = center + (size_t)B * Tin;
    float* inv    = amp    + (size_t)B * Tin;
    float* den    = inv    + (size_t)B * Tin;
    int*   lo     = (int*)(den + (size_t)B * Tout);
    int*   cnt    = lo + (size_t)B * Tout;

    detect_mask_mode_k<<<1, 256, 0, stream>>>(
        (const unsigned int*)mask, (B * Tin) / 4, mode);
    prep_k<<<B, Tin, 0, stream>>>(duration, sigma, mask, mode,
                                  center, amp, inv, Tin);
    denom_k<<<dim3((Tout + 255) / 256, B), 256, 0, stream>>>(
        center, amp, inv, den, lo, cnt, Tin, Tout);
    attn_k<<<B * Tin, 256, 0, stream>>>(center, amp, inv, den,
                                        out_attn, Tin, Tout);
    upsample_k<<<(B * Tout) / TILE_T, 256, 0, stream>>>(
        memory, center, amp, inv, den, lo, cnt, out_up, Tin, Tout, D);
}